// Round 1
// baseline (76.952 us; speedup 1.0000x reference)
//
#include <hip/hip_runtime.h>
#include <hip/hip_bf16.h>

// ---------------------------------------------------------------------------
// advantage = -0.5 * || T(flat) @ (actions-best) ||^2 per row, where
// flat = logits @ W^T + b, T = lower-tri scatter with squared diagonal.
// Fused: bf16 MFMA GEMM (M=65536, N=528->544pad, K=512) + in-LDS epilogue.
// ---------------------------------------------------------------------------

typedef __attribute__((ext_vector_type(8))) __bf16 bf16x8;
typedef __attribute__((ext_vector_type(4))) float f32x4;

#define AS1 __attribute__((address_space(1)))
#define AS3 __attribute__((address_space(3)))

__device__ __forceinline__ unsigned short f2b(float x) {
  unsigned u = __builtin_bit_cast(unsigned, x);
  u += 0x7fffu + ((u >> 16) & 1u);     // RNE; inputs are finite
  return (unsigned short)(u >> 16);
}
__device__ __forceinline__ float b2f(unsigned short h) {
  unsigned u = ((unsigned)h) << 16;
  return __builtin_bit_cast(float, u);
}

#define NFRAG 34              // 544 padded cols / 16
#define WTILE_BYTES 69632     // 34 frags * 2 kslices * 64 lanes * 16B
#define A_OFF 69632           // A-tile / diff region offset in LDS
#define SMEM_BYTES (69632 + 8192)

// --- prep: W [528][512] f32 -> fragment-linear bf16, padded to 544 rows ----
// WP[kstep][nfrag][ksl][lane][j] = bf16(W[nfrag*16+(lane&15)][kstep*64+ksl*32+(lane>>4)*8+j])
__global__ void prep_wp(const float* __restrict__ W, unsigned short* __restrict__ WP) {
  int t = blockIdx.x * 256 + threadIdx.x;   // [0, 34816)
  int lane = t & 63;
  int u = t >> 6;
  int ksl = u & 1;
  int v = u >> 1;                            // [0, 272)
  int nf = v % NFRAG;
  int kstep = v / NFRAG;
  int n = nf * 16 + (lane & 15);
  int k0 = kstep * 64 + ksl * 32 + (lane >> 4) * 8;
  unsigned short h[8];
  if (n < 528) {
    const float* src = W + (size_t)n * 512 + k0;
#pragma unroll
    for (int j = 0; j < 8; ++j) h[j] = f2b(src[j]);
  } else {
#pragma unroll
    for (int j = 0; j < 8; ++j) h[j] = 0;
  }
  uint4 p;
  p.x = (unsigned)h[0] | ((unsigned)h[1] << 16);
  p.y = (unsigned)h[2] | ((unsigned)h[3] << 16);
  p.z = (unsigned)h[4] | ((unsigned)h[5] << 16);
  p.w = (unsigned)h[6] | ((unsigned)h[7] << 16);
  *(uint4*)(WP + (size_t)t * 8) = p;
}

// --- main fused kernel ------------------------------------------------------
__global__ void __launch_bounds__(256, 2)
adv_kernel(const float* __restrict__ logits,
           const float* __restrict__ best,
           const float* __restrict__ actions,
           const float* __restrict__ bvec,
           const unsigned short* __restrict__ WP,
           float* __restrict__ out) {
  extern __shared__ char smem[];
  const int tid = threadIdx.x;
  const int l   = tid & 63;
  const int wid = tid >> 6;
  const int lr  = l & 15;
  const int lg  = l >> 4;
  const int brow = blockIdx.x * 64;
  const int start = wid * 8 + (wid > 0 ? 1 : 0);   // 0,9,17,25 (frags 17,25 duplicated)

  f32x4 acc[4][9];
  {
    f32x4 zero = {0.f, 0.f, 0.f, 0.f};
#pragma unroll
    for (int m = 0; m < 4; ++m)
#pragma unroll
      for (int n = 0; n < 9; ++n) acc[m][n] = zero;
  }

  const int ar = tid >> 2;            // staging row 0..63
  const int cq = (tid & 3) << 4;      // staging col base (elements)

  for (int ks = 0; ks < 8; ++ks) {
    // stage W tile: prepacked bf16 -> LDS, direct DMA, 16B/lane
    const char* wsrc = (const char*)WP + (size_t)ks * WTILE_BYTES;
#pragma unroll
    for (int q = 0; q < 17; ++q) {
      int off = ((q * 4 + wid) * 64) * 16;                       // wave-uniform
      __builtin_amdgcn_global_load_lds((AS1 unsigned int*)(wsrc + off + l * 16),
                                       (AS3 unsigned int*)(smem + off), 16, 0, 0);
    }
    // stage A tile: f32 -> bf16, XOR-swizzled rows of 128B
    {
      const float* src = logits + (size_t)(brow + ar) * 512 + ks * 64 + cq;
      float4 x0 = *(const float4*)(src + 0);
      float4 x1 = *(const float4*)(src + 4);
      float4 x2 = *(const float4*)(src + 8);
      float4 x3 = *(const float4*)(src + 12);
      uint4 p0, p1;
      p0.x = f2b(x0.x) | ((unsigned)f2b(x0.y) << 16);
      p0.y = f2b(x0.z) | ((unsigned)f2b(x0.w) << 16);
      p0.z = f2b(x1.x) | ((unsigned)f2b(x1.y) << 16);
      p0.w = f2b(x1.z) | ((unsigned)f2b(x1.w) << 16);
      p1.x = f2b(x2.x) | ((unsigned)f2b(x2.y) << 16);
      p1.y = f2b(x2.z) | ((unsigned)f2b(x2.w) << 16);
      p1.z = f2b(x3.x) | ((unsigned)f2b(x3.y) << 16);
      p1.w = f2b(x3.z) | ((unsigned)f2b(x3.w) << 16);
      char* abase = smem + A_OFF + ar * 128;
      int swz = (ar & 7) << 4;
      int cb  = cq * 2;
      *(uint4*)(abase + ((cb)      ^ swz)) = p0;
      *(uint4*)(abase + ((cb + 16) ^ swz)) = p1;
    }
    __syncthreads();
    // compute: 2 k-slices x 9 n-frags x 4 m-frags
#pragma unroll
    for (int ksl = 0; ksl < 2; ++ksl) {
      bf16x8 a[4];
#pragma unroll
      for (int m = 0; m < 4; ++m) {
        int arow = m * 16 + lr;
        int bcol = (ksl * 64 + lg * 16) ^ ((arow & 7) << 4);
        a[m] = *(const bf16x8*)(smem + A_OFF + arow * 128 + bcol);
      }
#pragma unroll
      for (int n = 0; n < 9; ++n) {
        int nf = start + n;
        bf16x8 bfr = *(const bf16x8*)(smem + ((nf * 2 + ksl) * 64 + l) * 16);
#pragma unroll
        for (int m = 0; m < 4; ++m)
          acc[m][n] = __builtin_amdgcn_mfma_f32_16x16x32_bf16(a[m], bfr, acc[m][n], 0, 0, 0);
      }
    }
    __syncthreads();
  }

  // epilogue: flat(+bias) -> bf16 LDS (overlays W region), diff -> LDS (overlays A)
  unsigned short* fl = (unsigned short*)smem;   // [64][532] bf16, row stride 1064B
#pragma unroll
  for (int n = 0; n < 9; ++n) {
    int nf = start + n;
    if (nf >= 33) continue;                     // nf==33 is pure padding
    int f = nf * 16 + lr;                       // < 528 guaranteed
    float bb = bvec[f];
#pragma unroll
    for (int m = 0; m < 4; ++m)
#pragma unroll
      for (int r = 0; r < 4; ++r) {
        int row = m * 16 + lg * 4 + r;          // C/D: col=lane&15, row=(lane>>4)*4+reg
        fl[row * 532 + f] = f2b(acc[m][n][r] + bb);
      }
  }
  {
    float* dl = (float*)(smem + A_OFF);         // [64][32] f32, XOR-swizzled per row
    int row = tid >> 2;
    int j0  = (tid & 3) << 3;
    const float* ap = actions + (size_t)(brow + row) * 32 + j0;
    const float* bp = best    + (size_t)(brow + row) * 32 + j0;
    float4 a0 = *(const float4*)(ap);
    float4 a1 = *(const float4*)(ap + 4);
    float4 b0 = *(const float4*)(bp);
    float4 b1 = *(const float4*)(bp + 4);
    float d[8] = {a0.x - b0.x, a0.y - b0.y, a0.z - b0.z, a0.w - b0.w,
                  a1.x - b1.x, a1.y - b1.y, a1.z - b1.z, a1.w - b1.w};
    int rs = row & 31;
#pragma unroll
    for (int q = 0; q < 8; ++q)
      dl[row * 32 + ((j0 + q) ^ rs)] = d[q];
  }
  __syncthreads();

  // per-row: vec[i] = sum_{j<i} flat[tri+j]*diff[j] + flat[tri+i]^2*diff[i]
  // 4 threads/row, i = (tid&3) + 4*ii (balanced); reduce with shfl_xor.
  {
    int it  = tid & 3;
    int row = tid >> 2;
    const unsigned short* flr = fl + row * 532;
    const float* dlr = (const float*)(smem + A_OFF) + row * 32;
    int rs = row & 31;
    float ssum = 0.f;
#pragma unroll
    for (int ii = 0; ii < 8; ++ii) {
      int i = it + ii * 4;
      int tri = (i * (i + 1)) >> 1;
      float vec = 0.f;
      for (int j = 0; j < i; ++j)
        vec += b2f(flr[tri + j]) * dlr[j ^ rs];
      float dv = b2f(flr[tri + i]);
      vec += dv * dv * dlr[i ^ rs];
      ssum += vec * vec;
    }
    ssum += __shfl_xor(ssum, 1);
    ssum += __shfl_xor(ssum, 2);
    if (it == 0) out[brow + row] = -0.5f * ssum;
  }
}

extern "C" void kernel_launch(void* const* d_in, const int* in_sizes, int n_in,
                              void* d_out, int out_size, void* d_ws, size_t ws_size,
                              hipStream_t stream) {
  const float* logits  = (const float*)d_in[0];
  const float* best    = (const float*)d_in[1];
  const float* actions = (const float*)d_in[2];
  const float* W       = (const float*)d_in[3];
  const float* bvec    = (const float*)d_in[4];
  float* out = (float*)d_out;
  unsigned short* WP = (unsigned short*)d_ws;   // needs 557056 B

  hipLaunchKernelGGL(prep_wp, dim3(136), dim3(256), 0, stream, W, WP);
  int M = in_sizes[0] / 512;                    // 65536 rows
  hipLaunchKernelGGL(adv_kernel, dim3(M / 64), dim3(256), SMEM_BYTES, stream,
                     logits, best, actions, bvec, WP, out);
}

// Round 2
// 61.817 us; speedup vs baseline: 1.2448x; 1.2448x over previous
//
#include <hip/hip_runtime.h>
#include <hip/hip_bf16.h>

// ---------------------------------------------------------------------------
// advantage = -0.5 * || T(flat) @ (actions-best) ||^2 per row, where
// flat = logits @ W^T + b, T = lower-tri scatter with squared diagonal.
// Round 2: BM=128/BK=32, 512-thread blocks, double-buffered 2-phase prefetch
// (stage t+1 before compute t), A staged as f32 via global_load_lds with
// pre-swizzled source, converted to bf16 at fragment read.
// ---------------------------------------------------------------------------

typedef __attribute__((ext_vector_type(8))) __bf16 bf16x8;
typedef __attribute__((ext_vector_type(4))) float f32x4;

#define AS1 __attribute__((address_space(1)))
#define AS3 __attribute__((address_space(3)))

__device__ __forceinline__ unsigned short f2b(float x) {
  unsigned u = __builtin_bit_cast(unsigned, x);
  u += 0x7fffu + ((u >> 16) & 1u);     // RNE; inputs are finite
  return (unsigned short)(u >> 16);
}
__device__ __forceinline__ float b2f(unsigned short h) {
  unsigned u = ((unsigned)h) << 16;
  return __builtin_bit_cast(float, u);
}

#define NFRAG 34                     // 544 padded cols / 16
#define WK_BYTES (NFRAG * 1024)      // 34816 B per BK=32 step (bf16 frag-linear)
#define ATILE_BYTES (128 * 32 * 4)   // 16384 B (f32, swizzled image)
#define BUF_BYTES (WK_BYTES + ATILE_BYTES)   // 51200
#define A_IN_BUF WK_BYTES
#define FLAT_STRIDE 532
#define DIFF_OFF (128 * FLAT_STRIDE * 2)     // 136192
#define SMEM_BYTES (DIFF_OFF + 128 * 32 * 4) // 152576 (>= 2*BUF_BYTES for GEMM)

// --- prep: W [528][512] f32 -> fragment-linear bf16, padded to 544 rows ----
// WP[k16][nf][lane][j] = bf16(W[nf*16+(lane&15)][k16*32+(lane>>4)*8+j])
__global__ void prep_wp(const float* __restrict__ W, unsigned short* __restrict__ WP) {
  int t = blockIdx.x * 256 + threadIdx.x;   // [0, 34816)
  int lane = t & 63;
  int u = t >> 6;                            // [0, 544)
  int nf = u % NFRAG;
  int k16 = u / NFRAG;                       // [0, 16)
  int n = nf * 16 + (lane & 15);
  int k0 = k16 * 32 + (lane >> 4) * 8;
  unsigned short h[8];
  if (n < 528) {
    const float* src = W + (size_t)n * 512 + k0;
#pragma unroll
    for (int j = 0; j < 8; ++j) h[j] = f2b(src[j]);
  } else {
#pragma unroll
    for (int j = 0; j < 8; ++j) h[j] = 0;
  }
  uint4 p;
  p.x = (unsigned)h[0] | ((unsigned)h[1] << 16);
  p.y = (unsigned)h[2] | ((unsigned)h[3] << 16);
  p.z = (unsigned)h[4] | ((unsigned)h[5] << 16);
  p.w = (unsigned)h[6] | ((unsigned)h[7] << 16);
  *(uint4*)(WP + (size_t)t * 8) = p;
}

// --- main fused kernel ------------------------------------------------------
__global__ void __launch_bounds__(512, 2)
adv_kernel(const float* __restrict__ logits,
           const float* __restrict__ best,
           const float* __restrict__ actions,
           const float* __restrict__ bvec,
           const unsigned short* __restrict__ WP,
           float* __restrict__ out) {
  extern __shared__ char smem[];
  const int tid = threadIdx.x;
  const int l   = tid & 63;
  const int wid = tid >> 6;
  const int lr  = l & 15;
  const int lg  = l >> 4;
  const int wc  = wid & 3;                 // N-split: 4 wave-cols
  const int wrbase = (wid >> 2) * 64;      // M-split: 2 wave-rows
  const int start = wc * 8 + (wc > 0 ? 1 : 0);  // 0,9,17,25 (frags 17,25 dup'd)
  const int brow = blockIdx.x * 128;

  f32x4 acc[4][9];
  {
    f32x4 zero = {0.f, 0.f, 0.f, 0.f};
#pragma unroll
    for (int m = 0; m < 4; ++m)
#pragma unroll
      for (int n = 0; n < 9; ++n) acc[m][n] = zero;
  }

  // per-thread fragment read offsets (A image XOR-swizzled at 16B granularity)
  int aoff[4][2];
#pragma unroll
  for (int m = 0; m < 4; ++m)
#pragma unroll
    for (int h = 0; h < 2; ++h)
      aoff[m][h] = (wrbase + m * 16 + lr) * 128 +
                   ((lg * 32 + h * 16) ^ ((lr & 7) << 4));
  int boff[9];
#pragma unroll
  for (int n = 0; n < 9; ++n) boff[n] = (start + n) * 1024 + l * 16;

  // staging: A first (HBM, long latency), then W (L2-resident after pass 1)
#define STAGE_A(dst, ks)                                                        \
  {                                                                             \
    char* dA = (dst) + A_IN_BUF;                                                \
    _Pragma("unroll")                                                           \
    for (int p = 0; p < 2; ++p) {                                               \
      int c = p * 512 + tid;                                                    \
      int row = c >> 3, hh = c & 7;                                             \
      const float* g = logits + (size_t)(brow + row) * 512 + (ks) * 32 +        \
                       ((hh ^ (row & 7)) << 2);                                 \
      __builtin_amdgcn_global_load_lds((AS1 unsigned int*)g,                    \
          (AS3 unsigned int*)(dA + (p * 512 + wid * 64) * 16), 16, 0, 0);       \
    }                                                                           \
  }
#define STAGE_W(dst, ks)                                                        \
  {                                                                             \
    const char* sW = (const char*)WP + (size_t)(ks) * WK_BYTES;                 \
    _Pragma("unroll")                                                           \
    for (int q = 0; q < 4; ++q) {                                               \
      int off = (q * 8 + wid) * 1024;                                           \
      __builtin_amdgcn_global_load_lds((AS1 unsigned int*)(sW + off + l * 16),  \
          (AS3 unsigned int*)((dst) + off), 16, 0, 0);                          \
    }                                                                           \
    if (wid < 2) {                                                              \
      int off = (32 + wid) * 1024;                                              \
      __builtin_amdgcn_global_load_lds((AS1 unsigned int*)(sW + off + l * 16),  \
          (AS3 unsigned int*)((dst) + off), 16, 0, 0);                          \
    }                                                                           \
  }

  STAGE_A(smem, 0)
  STAGE_W(smem, 0)
  __syncthreads();

  for (int t = 0; t < 16; ++t) {
    char* buf = smem + (t & 1) * BUF_BYTES;
    if (t < 15) {                       // prefetch next K-step into other buffer
      char* nb = smem + ((t & 1) ^ 1) * BUF_BYTES;
      STAGE_A(nb, t + 1)
      STAGE_W(nb, t + 1)
    }
    // A fragments: read f32 (swizzled image), convert to bf16 in-register
    bf16x8 a[4];
#pragma unroll
    for (int m = 0; m < 4; ++m) {
      f32x4 x0 = *(const f32x4*)(buf + A_IN_BUF + aoff[m][0]);
      f32x4 x1 = *(const f32x4*)(buf + A_IN_BUF + aoff[m][1]);
      bf16x8 af;
      af[0] = (__bf16)x0[0]; af[1] = (__bf16)x0[1];
      af[2] = (__bf16)x0[2]; af[3] = (__bf16)x0[3];
      af[4] = (__bf16)x1[0]; af[5] = (__bf16)x1[1];
      af[6] = (__bf16)x1[2]; af[7] = (__bf16)x1[3];
      a[m] = af;
    }
#pragma unroll
    for (int n = 0; n < 9; ++n) {
      bf16x8 bfr = *(const bf16x8*)(buf + boff[n]);
#pragma unroll
      for (int m = 0; m < 4; ++m)
        acc[m][n] = __builtin_amdgcn_mfma_f32_16x16x32_bf16(a[m], bfr, acc[m][n], 0, 0, 0);
    }
    if (t < 15) __syncthreads();        // drains vmcnt (prefetch) + lgkm
  }
  __syncthreads();                      // all ds_reads done before overlay

  // epilogue: flat(+bias) -> bf16 LDS [128][532]; diff -> f32 LDS (swizzled)
  unsigned short* fl = (unsigned short*)smem;
#pragma unroll
  for (int n = 0; n < 9; ++n) {
    int nf = start + n;
    if (nf >= 33) continue;             // frag 33 is pure padding
    int f = nf * 16 + lr;               // < 528
    float bb = bvec[f];
#pragma unroll
    for (int m = 0; m < 4; ++m)
#pragma unroll
      for (int r = 0; r < 4; ++r) {
        int row = wrbase + m * 16 + lg * 4 + r;  // C/D: col=lane&15, row=(lane>>4)*4+reg
        fl[row * FLAT_STRIDE + f] = f2b(acc[m][n][r] + bb);
      }
  }
  {
    float* dl = (float*)(smem + DIFF_OFF);       // [128][32] f32, XOR-swizzled
    int row = tid >> 2;
    int j0  = (tid & 3) << 3;
    const float* ap = actions + (size_t)(brow + row) * 32 + j0;
    const float* bp = best    + (size_t)(brow + row) * 32 + j0;
    float4 a0 = *(const float4*)(ap);
    float4 a1 = *(const float4*)(ap + 4);
    float4 b0 = *(const float4*)(bp);
    float4 b1 = *(const float4*)(bp + 4);
    float d[8] = {a0.x - b0.x, a0.y - b0.y, a0.z - b0.z, a0.w - b0.w,
                  a1.x - b1.x, a1.y - b1.y, a1.z - b1.z, a1.w - b1.w};
    int rs = row & 31;
#pragma unroll
    for (int q = 0; q < 8; ++q)
      dl[row * 32 + ((j0 + q) ^ rs)] = d[q];
  }
  __syncthreads();

  // per-row: vec[i] = sum_{j<i} flat[tri+j]*diff[j] + flat[tri+i]^2*diff[i]
  // 4 threads/row, i = (tid&3) + 4*ii (balanced); reduce with shfl_xor.
  {
    int it  = tid & 3;
    int row = tid >> 2;
    const unsigned short* flr = fl + row * FLAT_STRIDE;
    const float* dlr = (const float*)(smem + DIFF_OFF) + row * 32;
    int rs = row & 31;
    float ssum = 0.f;
#pragma unroll
    for (int ii = 0; ii < 8; ++ii) {
      int i = it + ii * 4;
      int tri = (i * (i + 1)) >> 1;
      float vec = 0.f;
      for (int j = 0; j < i; ++j)
        vec += b2f(flr[tri + j]) * dlr[j ^ rs];
      float dv = b2f(flr[tri + i]);
      vec += dv * dv * dlr[i ^ rs];
      ssum += vec * vec;
    }
    ssum += __shfl_xor(ssum, 1);
    ssum += __shfl_xor(ssum, 2);
    if (it == 0) out[brow + row] = -0.5f * ssum;
  }
}

extern "C" void kernel_launch(void* const* d_in, const int* in_sizes, int n_in,
                              void* d_out, int out_size, void* d_ws, size_t ws_size,
                              hipStream_t stream) {
  const float* logits  = (const float*)d_in[0];
  const float* best    = (const float*)d_in[1];
  const float* actions = (const float*)d_in[2];
  const float* W       = (const float*)d_in[3];
  const float* bvec    = (const float*)d_in[4];
  float* out = (float*)d_out;
  unsigned short* WP = (unsigned short*)d_ws;   // needs 557056 B

  hipLaunchKernelGGL(prep_wp, dim3(136), dim3(256), 0, stream, W, WP);
  int M = in_sizes[0] / 512;                    // 65536 rows
  hipLaunchKernelGGL(adv_kernel, dim3(M / 128), dim3(512), SMEM_BYTES, stream,
                     logits, best, actions, bvec, WP, out);
}